// Round 1
// baseline (807.050 us; speedup 1.0000x reference)
//
#include <hip/hip_runtime.h>
#include <hip/hip_bf16.h>

// Problem constants (from setup_inputs): B=32, T=512, C=F=384, M=2048.
#define B_ 32
#define T_ 512
#define C_ 384
#define F_ 384
#define M_ 2048

constexpr int BM  = 32;        // output rows (t) per block
constexpr int NT  = 384;       // threads per block = F (one column per thread)
constexpr int NW  = NT / 64;   // waves per block
constexpr int CCH = 96;        // c-chunk staged in LDS per iteration
constexpr int XR  = BM + 2;    // staged rows incl. conv halo
constexpr int XP  = CCH + 4;   // LDS row stride (floats)

// ---------------------------------------------------------------------------
// wT[(k*C + c)*F + f] = w[(f*C + c)*3 + k]   (torch [F,C,3] -> [3,C,F])
__global__ void transpose_w_kernel(const float* __restrict__ w,
                                   float* __restrict__ wT) {
  int o = blockIdx.x * 256 + threadIdx.x;
  if (o >= 3 * C_ * F_) return;
  int k   = o / (C_ * F_);
  int rem = o - k * (C_ * F_);
  int c   = rem / F_;
  int f   = rem - c * F_;
  wT[o] = w[(f * C_ + c) * 3 + k];
}

// ---------------------------------------------------------------------------
// Fused conv1d(K=3,pad=1) + bias + ReLU + LayerNorm.
// FUSE=false: writes LN output [B,T,F] to `out`.
// FUSE=true : additionally fuses final linear (wl,bl) + mask -> out is dpo [B,T].
template <bool FUSE>
__global__ __launch_bounds__(NT) void conv_ln_kernel(
    const float* __restrict__ xin,      // [B,T,C]
    const float* __restrict__ mask_in,  // [B,T] or nullptr
    const float* __restrict__ wT,       // [3,C,F]
    const float* __restrict__ bias,     // [F]
    const float* __restrict__ gamma,    // [F]
    const float* __restrict__ beta,     // [F]
    const float* __restrict__ wl,       // [F]   (FUSE only)
    const float* __restrict__ bl,       // [1]   (FUSE only)
    const float* __restrict__ mask_out, // [B,T] (FUSE only)
    float* __restrict__ out) {
  __shared__ float xt[XR][XP];
  __shared__ float red[BM][NW][2];
  __shared__ float stats[BM][2];

  const int tid  = threadIdx.x;
  const int f    = tid;
  const int lane = tid & 63;
  const int wid  = tid >> 6;
  const int blk  = blockIdx.x;          // 0 .. B*T/BM-1
  const int b    = blk / (T_ / BM);
  const int t0   = (blk % (T_ / BM)) * BM;

  float acc[BM];
#pragma unroll
  for (int r = 0; r < BM; ++r) acc[r] = 0.f;

  for (int cb = 0; cb < C_; cb += CCH) {
    __syncthreads();  // protect xt from previous chunk's readers
    // Stage x[b][t0-1 .. t0+BM][cb .. cb+CCH) into LDS (zero-padded, masked).
    for (int e = tid; e < XR * (CCH / 4); e += NT) {
      int r  = e / (CCH / 4);
      int c4 = e - r * (CCH / 4);
      int t  = t0 - 1 + r;
      float4 v = make_float4(0.f, 0.f, 0.f, 0.f);
      if (t >= 0 && t < T_) {
        v = *(const float4*)(xin + ((size_t)b * T_ + t) * C_ + cb + c4 * 4);
        if (mask_in) {
          float m = mask_in[b * T_ + t];
          v.x *= m; v.y *= m; v.z *= m; v.w *= m;
        }
      }
      *(float4*)&xt[r][c4 * 4] = v;
    }
    __syncthreads();

    for (int cc4 = 0; cc4 < CCH / 4; ++cc4) {
      float wk[3][4];
#pragma unroll
      for (int k = 0; k < 3; ++k)
#pragma unroll
        for (int j = 0; j < 4; ++j)
          wk[k][j] = wT[((size_t)k * C_ + cb + cc4 * 4 + j) * F_ + f];

#pragma unroll
      for (int i = 0; i < XR; ++i) {
        float4 xv = *(const float4*)&xt[i][cc4 * 4];
        // xt row i (global t0-1+i) with tap k contributes to output row i-k.
        if (i < BM)
          acc[i] += xv.x * wk[0][0] + xv.y * wk[0][1] + xv.z * wk[0][2] + xv.w * wk[0][3];
        if (i >= 1 && (i - 1) < BM)
          acc[i - 1] += xv.x * wk[1][0] + xv.y * wk[1][1] + xv.z * wk[1][2] + xv.w * wk[1][3];
        if (i >= 2)
          acc[i - 2] += xv.x * wk[2][0] + xv.y * wk[2][1] + xv.z * wk[2][2] + xv.w * wk[2][3];
      }
    }
  }

  // bias + ReLU
  const float bf = bias[f];
#pragma unroll
  for (int r = 0; r < BM; ++r) acc[r] = fmaxf(acc[r] + bf, 0.f);

  // per-row mean/var across f (384 threads): wave butterfly + LDS partials
#pragma unroll
  for (int r = 0; r < BM; ++r) {
    float s = acc[r], s2 = acc[r] * acc[r];
#pragma unroll
    for (int off = 32; off; off >>= 1) {
      s  += __shfl_xor(s, off);
      s2 += __shfl_xor(s2, off);
    }
    if (lane == 0) { red[r][wid][0] = s; red[r][wid][1] = s2; }
  }
  __syncthreads();
  if (tid < BM) {
    float s = 0.f, s2 = 0.f;
#pragma unroll
    for (int w = 0; w < NW; ++w) { s += red[tid][w][0]; s2 += red[tid][w][1]; }
    float mu  = s / F_;
    float var = s2 / F_ - mu * mu;
    stats[tid][0] = mu;
    stats[tid][1] = rsqrtf(var + 1e-5f);
  }
  __syncthreads();

  const float g  = gamma[f];
  const float be = beta[f];
  if (!FUSE) {
#pragma unroll
    for (int r = 0; r < BM; ++r) {
      float ln = (acc[r] - stats[r][0]) * stats[r][1] * g + be;
      out[((size_t)b * T_ + t0 + r) * F_ + f] = ln;
    }
  } else {
    const float wlf = wl[f];
#pragma unroll
    for (int r = 0; r < BM; ++r) {
      float ln = (acc[r] - stats[r][0]) * stats[r][1] * g + be;
      float p  = ln * wlf;
#pragma unroll
      for (int off = 32; off; off >>= 1) p += __shfl_xor(p, off);
      if (lane == 0) red[r][wid][0] = p;
    }
    __syncthreads();
    if (tid < BM) {
      float s = 0.f;
#pragma unroll
      for (int w = 0; w < NW; ++w) s += red[tid][w][0];
      int t = t0 + tid;
      out[b * T_ + t] = (s + bl[0]) * mask_out[b * T_ + t];
    }
  }
}

// ---------------------------------------------------------------------------
// Inclusive cumsum of target[b][:] -> cs[b][:]. One wave per batch row.
__global__ void cumsum_kernel(const int* __restrict__ target,
                              int* __restrict__ cs) {
  int b    = blockIdx.x;
  int lane = threadIdx.x;  // 0..63
  int base = b * T_ + lane * 8;
  int v[8];
#pragma unroll
  for (int i = 0; i < 8; ++i) v[i] = target[base + i];
#pragma unroll
  for (int i = 1; i < 8; ++i) v[i] += v[i - 1];
  int tot = v[7];
  int inc = tot;
#pragma unroll
  for (int d = 1; d < 64; d <<= 1) {
    int t = __shfl_up(inc, d);
    if (lane >= d) inc += t;
  }
  int excl = inc - tot;
#pragma unroll
  for (int i = 0; i < 8; ++i) cs[base + i] = v[i] + excl;
}

// ---------------------------------------------------------------------------
// Expansion: one wave per output frame. Binary search cumsum, copy 384 floats.
__global__ __launch_bounds__(256) void expand_kernel(
    const float* __restrict__ enc,  // [B,T,C]
    const int* __restrict__ cs,     // [B,T]
    float* __restrict__ out,        // [B,M,C]
    float* __restrict__ dec) {      // [B,M] (written as float)
  __shared__ int scs[T_];
  const int blk = blockIdx.x;                 // B * (M/4) blocks
  const int b   = blk / (M_ / 4);
  const int p0  = (blk - b * (M_ / 4)) * 4;
  for (int i = threadIdx.x; i < T_; i += 256) scs[i] = cs[b * T_ + i];
  __syncthreads();

  const int lane = threadIdx.x & 63;
  const int wid  = threadIdx.x >> 6;
  const int pos  = p0 + wid;
  const int total = scs[T_ - 1];
  const bool valid = pos < total;

  // searchsorted(cs, pos, 'right'): count of cs[i] <= pos
  int idx = 0;
#pragma unroll
  for (int step = 512; step; step >>= 1)
    if (idx + step <= T_ && scs[idx + step - 1] <= pos) idx += step;
  int src = idx < T_ ? idx : T_ - 1;

  const float4* srow = (const float4*)(enc + ((size_t)b * T_ + src) * C_);
  float4* orow = (float4*)(out + ((size_t)b * M_ + pos) * C_);
  const float4 zero = make_float4(0.f, 0.f, 0.f, 0.f);
#pragma unroll
  for (int j = 0; j < 2; ++j) {
    int c4 = j * 64 + lane;
    if (c4 < C_ / 4) orow[c4] = valid ? srow[c4] : zero;
  }
  if (lane == 0) dec[b * M_ + pos] = valid ? (float)(pos + 1) : 0.f;
}

// ---------------------------------------------------------------------------
extern "C" void kernel_launch(void* const* d_in, const int* in_sizes, int n_in,
                              void* d_out, int out_size, void* d_ws,
                              size_t ws_size, hipStream_t stream) {
  const float* enc    = (const float*)d_in[0];
  const float* mask   = (const float*)d_in[1];   // [B,T,1]
  const int*   target = (const int*)d_in[2];
  // d_in[3] = mel_max_length (2048, hardcoded)
  const float* w1    = (const float*)d_in[4];
  const float* b1    = (const float*)d_in[5];
  const float* g1    = (const float*)d_in[6];
  const float* beta1 = (const float*)d_in[7];
  const float* w2    = (const float*)d_in[8];
  const float* b2    = (const float*)d_in[9];
  const float* g2    = (const float*)d_in[10];
  const float* beta2 = (const float*)d_in[11];
  const float* wl    = (const float*)d_in[12];
  const float* bl    = (const float*)d_in[13];

  // Workspace layout (floats): wT1 | wT2 | x1 | cs
  float* ws  = (float*)d_ws;
  float* wT1 = ws;
  float* wT2 = wT1 + 3 * C_ * F_;
  float* x1  = wT2 + 3 * C_ * F_;
  int*   cs  = (int*)(x1 + (size_t)B_ * T_ * F_);

  // Output layout (all read back as f32): out0 [B,M,C] | dec [B,M] | dpo [B,T]
  float* out0 = (float*)d_out;
  float* dec  = out0 + (size_t)B_ * M_ * C_;
  float* dpo  = dec + (size_t)B_ * M_;

  const int wtotal = 3 * C_ * F_;
  transpose_w_kernel<<<(wtotal + 255) / 256, 256, 0, stream>>>(w1, wT1);
  transpose_w_kernel<<<(wtotal + 255) / 256, 256, 0, stream>>>(w2, wT2);

  const int nblk = (B_ * T_) / BM;  // 512
  conv_ln_kernel<false><<<nblk, NT, 0, stream>>>(
      enc, mask, wT1, b1, g1, beta1, nullptr, nullptr, nullptr, x1);
  conv_ln_kernel<true><<<nblk, NT, 0, stream>>>(
      x1, nullptr, wT2, b2, g2, beta2, wl, bl, mask, dpo);

  cumsum_kernel<<<B_, 64, 0, stream>>>(target, cs);
  expand_kernel<<<(B_ * M_) / 4, 256, 0, stream>>>(enc, cs, out0, dec);
}

// Round 2
// 140.818 us; speedup vs baseline: 5.7312x; 5.7312x over previous
//
#include <hip/hip_runtime.h>
#include <hip/hip_bf16.h>
#include <stdint.h>

// Problem constants: B=32, T=512, C=F=384, M=2048.
#define B_ 32
#define T_ 512
#define C_ 384
#define F_ 384
#define M_ 2048
#define PT (T_ + 2)      // padded time rows per batch (halo for K=3 conv)
#define KTOT (3 * C_)    // GEMM K = 1152

typedef __bf16 bf16x8 __attribute__((ext_vector_type(8)));
typedef float  f32x4  __attribute__((ext_vector_type(4)));
typedef unsigned short ushort_t;

__device__ __forceinline__ float bf2f(uint32_t bits16) {
  union { uint32_t u; float f; } c; c.u = bits16 << 16; return c.f;
}
__device__ __forceinline__ ushort_t f2bf(float f) {
  __hip_bfloat16 h = __float2bfloat16(f);
  return *reinterpret_cast<ushort_t*>(&h);
}
__device__ __forceinline__ void gload16(const void* g, void* l) {
  __builtin_amdgcn_global_load_lds(
      (const __attribute__((address_space(1))) uint32_t*)g,
      (__attribute__((address_space(3))) uint32_t*)l, 16, 0, 0);
}

// ---------------------------------------------------------------------------
// xm[b][pr][c] = (1<=pr<=T) ? bf16(x[b][pr-1][c] * mask[b][pr-1]) : 0
__global__ __launch_bounds__(256) void prep_x_kernel(
    const float* __restrict__ x, const float* __restrict__ mask,
    ushort_t* __restrict__ xm) {
  int i = blockIdx.x * 256 + threadIdx.x;  // one thread per 4 elems
  int r = i / (C_ / 4);
  if (r >= B_ * PT) return;
  int c4 = (i % (C_ / 4)) * 4;
  int b = r / PT, pr = r % PT;
  uint32_t p0 = 0, p1 = 0;
  if (pr >= 1 && pr <= T_) {
    int t = pr - 1;
    const float4 v = *(const float4*)(x + ((size_t)b * T_ + t) * C_ + c4);
    float m = mask[b * T_ + t];
    p0 = (uint32_t)f2bf(v.x * m) | ((uint32_t)f2bf(v.y * m) << 16);
    p1 = (uint32_t)f2bf(v.z * m) | ((uint32_t)f2bf(v.w * m) << 16);
  }
  *(uint2*)(xm + (size_t)r * C_ + c4) = make_uint2(p0, p1);
}

// wt[n][kk*C + c] = bf16(w[n][c][kk])   (torch [F,C,3] -> [F, 3*C] kk-major)
__global__ __launch_bounds__(256) void prep_w_kernel(
    const float* __restrict__ w, ushort_t* __restrict__ wt) {
  int o = blockIdx.x * 256 + threadIdx.x;
  if (o >= F_ * KTOT) return;
  int n = o / KTOT, rem = o % KTOT, kk = rem / C_, c = rem % C_;
  wt[o] = f2bf(w[(n * C_ + c) * 3 + kk]);
}

// ---------------------------------------------------------------------------
// GEMM: out[m][n] = relu( sum_k Wt[n][k] * X[m][k] + bias[n] ), bf16 out.
// X[m][k=kk*C+c] = xp[b][t0+m+kk][c]  (implicit conv window via padded input).
// D computed as [n][m] (A = W rows, B = X rows; both frags contiguous in k).
constexpr int G_BN = 64, G_BM = 128, G_KS = 64, G_NT = 256;

__global__ __launch_bounds__(G_NT, 3) void gemm_kernel(
    const ushort_t* __restrict__ xp,   // [B][PT][C] bf16 (zero halo rows)
    const ushort_t* __restrict__ wt,   // [F][KTOT] bf16
    const float* __restrict__ bias,    // [F]
    ushort_t* __restrict__ out) {      // [B*T][F] bf16
  __shared__ char lds[(G_BN + G_BM) * G_KS * 2];
  char* ldsW = lds;                       // [64][64] bf16, row = 128 B
  char* ldsX = lds + G_BN * G_KS * 2;     // [128][64] bf16

  const int tid = threadIdx.x;
  const int l = tid & 63, q = l >> 4, r16 = l & 15;
  const int wid = tid >> 6, wn = wid & 1, wm = wid >> 1;
  const int bid = blockIdx.x;
  const int nt = bid % 6, mt = bid / 6;
  const int n0 = nt * G_BN;
  const int b = mt >> 2, t0 = (mt & 3) * G_BM;
  const ushort_t* xb = xp + (size_t)b * PT * C_;

  f32x4 acc[2][4];
#pragma unroll
  for (int fn = 0; fn < 2; ++fn)
#pragma unroll
    for (int fm = 0; fm < 4; ++fm) acc[fn][fm] = (f32x4){0.f, 0.f, 0.f, 0.f};

  for (int s = 0; s < 18; ++s) {
    const int kk = s / 6, c0 = (s % 6) * G_KS;
    __syncthreads();  // previous tile's readers done
    // Stage W tile (2 x 4KB) and X tile (4 x 4KB), 16B/lane, linear LDS dest,
    // XOR-swizzled (chunk ^= row&7) via pre-swizzled global source (rule 21).
#pragma unroll
    for (int i = 0; i < 2; ++i) {
      int lin = i * 4096 + tid * 16;
      int row = lin >> 7, ch = ((lin >> 4) & 7) ^ (row & 7);
      gload16(wt + (size_t)(n0 + row) * KTOT + kk * C_ + c0 + ch * 8,
              ldsW + i * 4096 + (wid << 10));
    }
#pragma unroll
    for (int i = 0; i < 4; ++i) {
      int lin = i * 4096 + tid * 16;
      int row = lin >> 7, ch = ((lin >> 4) & 7) ^ (row & 7);
      gload16(xb + (size_t)(t0 + row + kk) * C_ + c0 + ch * 8,
              ldsX + i * 4096 + (wid << 10));
    }
    __syncthreads();  // staging complete (compiler drains vmcnt at barrier)

#pragma unroll
    for (int ks = 0; ks < 2; ++ks) {
      bf16x8 af[2], bx[4];
#pragma unroll
      for (int fn = 0; fn < 2; ++fn) {
        int rr = wn * 32 + fn * 16 + r16;
        int ch = (ks * 4 + q) ^ (rr & 7);
        af[fn] = *(const bf16x8*)(ldsW + rr * 128 + ch * 16);
      }
#pragma unroll
      for (int fm = 0; fm < 4; ++fm) {
        int rr = wm * 64 + fm * 16 + r16;
        int ch = (ks * 4 + q) ^ (rr & 7);
        bx[fm] = *(const bf16x8*)(ldsX + rr * 128 + ch * 16);
      }
#pragma unroll
      for (int fn = 0; fn < 2; ++fn)
#pragma unroll
        for (int fm = 0; fm < 4; ++fm)
          acc[fn][fm] = __builtin_amdgcn_mfma_f32_16x16x32_bf16(
              af[fn], bx[fm], acc[fn][fm], 0, 0, 0);
    }
  }

  // Epilogue: D[n][m], n = n0+wn*32+fn*16+q*4+reg, m = mt*128+wm*64+fm*16+r16.
  const int mbase = mt * G_BM + wm * 64 + r16;
#pragma unroll
  for (int fn = 0; fn < 2; ++fn) {
    const int nb = n0 + wn * 32 + fn * 16 + q * 4;
    float b0 = bias[nb], b1 = bias[nb + 1], b2 = bias[nb + 2], b3 = bias[nb + 3];
#pragma unroll
    for (int fm = 0; fm < 4; ++fm) {
      const int m = mbase + fm * 16;
      uint32_t p0 = (uint32_t)f2bf(fmaxf(acc[fn][fm][0] + b0, 0.f)) |
                    ((uint32_t)f2bf(fmaxf(acc[fn][fm][1] + b1, 0.f)) << 16);
      uint32_t p1 = (uint32_t)f2bf(fmaxf(acc[fn][fm][2] + b2, 0.f)) |
                    ((uint32_t)f2bf(fmaxf(acc[fn][fm][3] + b3, 0.f)) << 16);
      *(uint2*)(out + (size_t)m * F_ + nb) = make_uint2(p0, p1);
    }
  }
}

// ---------------------------------------------------------------------------
// LayerNorm over F=384. LAST=false: write bf16 into padded x1p rows 1..T.
// LAST=true: fuse final linear (wl,bl) + output mask -> dpo [B*T] f32.
template <bool LAST>
__global__ __launch_bounds__(256) void ln_kernel(
    const ushort_t* __restrict__ yin,  // [B*T][F] bf16
    const float* __restrict__ g, const float* __restrict__ be,
    const float* __restrict__ wl, const float* __restrict__ bl,
    const float* __restrict__ mask,    // [B*T]
    ushort_t* __restrict__ xout,       // [B][PT][C] bf16 (LAST=false)
    float* __restrict__ dpo) {         // [B*T]       (LAST=true)
  const int row = blockIdx.x * 4 + (threadIdx.x >> 6);
  const int l = threadIdx.x & 63;
  const uint32_t* yrow = (const uint32_t*)(yin + (size_t)row * F_);
  uint32_t u[3];
  float v[6];
#pragma unroll
  for (int j = 0; j < 3; ++j) u[j] = yrow[l + j * 64];
#pragma unroll
  for (int j = 0; j < 3; ++j) {
    v[2 * j] = bf2f(u[j] & 0xffffu);
    v[2 * j + 1] = bf2f(u[j] >> 16);
  }
  float s = 0.f, s2 = 0.f;
#pragma unroll
  for (int j = 0; j < 6; ++j) { s += v[j]; s2 += v[j] * v[j]; }
#pragma unroll
  for (int off = 32; off; off >>= 1) {
    s += __shfl_xor(s, off);
    s2 += __shfl_xor(s2, off);
  }
  const float mu = s / F_;
  const float rs = rsqrtf(s2 / F_ - mu * mu + 1e-5f);
  if (!LAST) {
    const int b = row >> 9, t = row & 511;
    uint32_t* orow = (uint32_t*)(xout + ((size_t)(b * PT + 1 + t)) * C_);
#pragma unroll
    for (int j = 0; j < 3; ++j) {
      int n = (l + j * 64) * 2;
      float a0 = (v[2 * j] - mu) * rs * g[n] + be[n];
      float a1 = (v[2 * j + 1] - mu) * rs * g[n + 1] + be[n + 1];
      orow[l + j * 64] = (uint32_t)f2bf(a0) | ((uint32_t)f2bf(a1) << 16);
    }
  } else {
    float p = 0.f;
#pragma unroll
    for (int j = 0; j < 3; ++j) {
      int n = (l + j * 64) * 2;
      p += ((v[2 * j] - mu) * rs * g[n] + be[n]) * wl[n];
      p += ((v[2 * j + 1] - mu) * rs * g[n + 1] + be[n + 1]) * wl[n + 1];
    }
#pragma unroll
    for (int off = 32; off; off >>= 1) p += __shfl_xor(p, off);
    if (l == 0) dpo[row] = (p + bl[0]) * mask[row];
  }
}

// ---------------------------------------------------------------------------
__global__ void cumsum_kernel(const int* __restrict__ target,
                              int* __restrict__ cs) {
  int b = blockIdx.x;
  int lane = threadIdx.x;  // 0..63
  int base = b * T_ + lane * 8;
  int v[8];
#pragma unroll
  for (int i = 0; i < 8; ++i) v[i] = target[base + i];
#pragma unroll
  for (int i = 1; i < 8; ++i) v[i] += v[i - 1];
  int tot = v[7];
  int inc = tot;
#pragma unroll
  for (int d = 1; d < 64; d <<= 1) {
    int t = __shfl_up(inc, d);
    if (lane >= d) inc += t;
  }
  int excl = inc - tot;
#pragma unroll
  for (int i = 0; i < 8; ++i) cs[base + i] = v[i] + excl;
}

__global__ __launch_bounds__(256) void expand_kernel(
    const float* __restrict__ enc,  // [B,T,C] f32
    const int* __restrict__ cs,     // [B,T]
    float* __restrict__ out,        // [B,M,C]
    float* __restrict__ dec) {      // [B,M] (as float)
  __shared__ int scs[T_];
  const int blk = blockIdx.x;  // B * (M/4) blocks
  const int b = blk / (M_ / 4);
  const int p0 = (blk - b * (M_ / 4)) * 4;
  for (int i = threadIdx.x; i < T_; i += 256) scs[i] = cs[b * T_ + i];
  __syncthreads();

  const int lane = threadIdx.x & 63;
  const int wid = threadIdx.x >> 6;
  const int pos = p0 + wid;
  const int total = scs[T_ - 1];
  const bool valid = pos < total;

  int idx = 0;
#pragma unroll
  for (int step = 512; step; step >>= 1)
    if (idx + step <= T_ && scs[idx + step - 1] <= pos) idx += step;
  int src = idx < T_ ? idx : T_ - 1;

  const float4* srow = (const float4*)(enc + ((size_t)b * T_ + src) * C_);
  float4* orow = (float4*)(out + ((size_t)b * M_ + pos) * C_);
  const float4 zero = make_float4(0.f, 0.f, 0.f, 0.f);
#pragma unroll
  for (int j = 0; j < 2; ++j) {
    int c4 = j * 64 + lane;
    if (c4 < C_ / 4) orow[c4] = valid ? srow[c4] : zero;
  }
  if (lane == 0) dec[b * M_ + pos] = valid ? (float)(pos + 1) : 0.f;
}

// ---------------------------------------------------------------------------
extern "C" void kernel_launch(void* const* d_in, const int* in_sizes, int n_in,
                              void* d_out, int out_size, void* d_ws,
                              size_t ws_size, hipStream_t stream) {
  const float* enc    = (const float*)d_in[0];
  const float* mask   = (const float*)d_in[1];
  const int*   target = (const int*)d_in[2];
  const float* w1    = (const float*)d_in[4];
  const float* b1    = (const float*)d_in[5];
  const float* g1    = (const float*)d_in[6];
  const float* beta1 = (const float*)d_in[7];
  const float* w2    = (const float*)d_in[8];
  const float* b2    = (const float*)d_in[9];
  const float* g2    = (const float*)d_in[10];
  const float* beta2 = (const float*)d_in[11];
  const float* wl    = (const float*)d_in[12];
  const float* bl    = (const float*)d_in[13];

  // Workspace (bf16 unless noted): xm (padded, reused as x1p) | conv | wt1 | wt2 | cs
  ushort_t* xm   = (ushort_t*)d_ws;                   // [B][PT][C]
  ushort_t* conv = xm + (size_t)B_ * PT * C_;         // [B*T][F]
  ushort_t* wt1  = conv + (size_t)B_ * T_ * F_;       // [F][KTOT]
  ushort_t* wt2  = wt1 + (size_t)F_ * KTOT;
  int*      cs   = (int*)(wt2 + (size_t)F_ * KTOT);   // [B][T] i32

  float* out0 = (float*)d_out;                        // [B,M,C]
  float* dec  = out0 + (size_t)B_ * M_ * C_;          // [B,M]
  float* dpo  = dec + (size_t)B_ * M_;                // [B,T]

  prep_x_kernel<<<(B_ * PT * (C_ / 4) + 255) / 256, 256, 0, stream>>>(enc, mask, xm);
  prep_w_kernel<<<(F_ * KTOT + 255) / 256, 256, 0, stream>>>(w1, wt1);
  prep_w_kernel<<<(F_ * KTOT + 255) / 256, 256, 0, stream>>>(w2, wt2);

  const int gblk = (F_ / G_BN) * ((B_ * T_) / G_BM);  // 6 * 128 = 768
  gemm_kernel<<<gblk, G_NT, 0, stream>>>(xm, wt1, b1, conv);
  ln_kernel<false><<<(B_ * T_) / 4, 256, 0, stream>>>(
      conv, g1, beta1, nullptr, nullptr, nullptr, xm, nullptr);
  gemm_kernel<<<gblk, G_NT, 0, stream>>>(xm, wt2, b2, conv);
  ln_kernel<true><<<(B_ * T_) / 4, 256, 0, stream>>>(
      conv, g2, beta2, wl, bl, mask, nullptr, dpo);

  cumsum_kernel<<<B_, 64, 0, stream>>>(target, cs);
  expand_kernel<<<(B_ * M_) / 4, 256, 0, stream>>>(enc, cs, out0, dec);
}

// Round 3
// 104.374 us; speedup vs baseline: 7.7323x; 1.3492x over previous
//
#include <hip/hip_runtime.h>
#include <hip/hip_bf16.h>
#include <stdint.h>

// Problem constants: B=32, T=512, C=F=384, M=2048.
#define B_ 32
#define T_ 512
#define C_ 384
#define F_ 384
#define M_ 2048
#define PT (T_ + 2)      // padded time rows per batch (halo for K=3 conv)
#define KTOT (3 * C_)    // GEMM K = 1152

typedef __bf16 bf16x8 __attribute__((ext_vector_type(8)));
typedef float  f32x4  __attribute__((ext_vector_type(4)));
typedef unsigned short ushort_t;

__device__ __forceinline__ float bf2f(uint32_t bits16) {
  union { uint32_t u; float f; } c; c.u = bits16 << 16; return c.f;
}
__device__ __forceinline__ ushort_t f2bf(float f) {
  __hip_bfloat16 h = __float2bfloat16(f);
  return *reinterpret_cast<ushort_t*>(&h);
}
__device__ __forceinline__ void gload16(const void* g, void* l) {
  __builtin_amdgcn_global_load_lds(
      (const __attribute__((address_space(1))) uint32_t*)g,
      (__attribute__((address_space(3))) uint32_t*)l, 16, 0, 0);
}

// ---------------------------------------------------------------------------
// Fused prep: 3 grid regions.
//  A: xm[b][pr][c] = (1<=pr<=T) ? bf16(x[b][pr-1][c]*mask[b][pr-1]) : 0,
//     and zero the halo rows of x1p (rows pr==0 and pr==T+1).
//  B: wtX[n][kk*C+c] = bf16(wX[n][c][kk])  for both weights.
//  C: cumsum of target rows.
#define NXB 6168   // = B*PT*(C/4)/256
#define NWB 3456   // = 2*F*KTOT/256
__global__ __launch_bounds__(256) void prep_kernel(
    const float* __restrict__ x, const float* __restrict__ mask,
    const int* __restrict__ target,
    const float* __restrict__ w1, const float* __restrict__ w2,
    ushort_t* __restrict__ xm, ushort_t* __restrict__ x1p,
    ushort_t* __restrict__ wt1, ushort_t* __restrict__ wt2,
    int* __restrict__ cs) {
  const int gid = blockIdx.x;
  const int tid = threadIdx.x;
  if (gid < NXB) {
    int i = gid * 256 + tid;            // one thread per 4 channels
    int r = i / (C_ / 4);
    int c4 = (i % (C_ / 4)) * 4;
    int b = r / PT, pr = r % PT;
    uint32_t p0 = 0, p1 = 0;
    if (pr >= 1 && pr <= T_) {
      int t = pr - 1;
      const float4 v = *(const float4*)(x + ((size_t)b * T_ + t) * C_ + c4);
      float m = mask[b * T_ + t];
      p0 = (uint32_t)f2bf(v.x * m) | ((uint32_t)f2bf(v.y * m) << 16);
      p1 = (uint32_t)f2bf(v.z * m) | ((uint32_t)f2bf(v.w * m) << 16);
    } else {
      // halo row: x1p needs zeros too (gemm1 only writes rows 1..T)
      *(uint2*)(x1p + (size_t)r * C_ + c4) = make_uint2(0, 0);
    }
    *(uint2*)(xm + (size_t)r * C_ + c4) = make_uint2(p0, p1);
  } else if (gid < NXB + NWB) {
    int idx = (gid - NXB) * 256 + tid;  // 0 .. 2*F*KTOT
    int w = idx >= F_ * KTOT;
    int o = idx - (w ? F_ * KTOT : 0);
    int n = o / KTOT, rem = o % KTOT, kk = rem / C_, c = rem % C_;
    const float* src = w ? w2 : w1;
    ushort_t* dst = w ? wt2 : wt1;
    dst[o] = f2bf(src[(n * C_ + c) * 3 + kk]);
  } else {
    int b = (gid - NXB - NWB) * 4 + (tid >> 6);
    int lane = tid & 63;
    int base = b * T_ + lane * 8;
    int v[8];
#pragma unroll
    for (int i = 0; i < 8; ++i) v[i] = target[base + i];
#pragma unroll
    for (int i = 1; i < 8; ++i) v[i] += v[i - 1];
    int tot = v[7];
    int inc = tot;
#pragma unroll
    for (int d = 1; d < 64; d <<= 1) {
      int t = __shfl_up(inc, d);
      if (lane >= d) inc += t;
    }
    int excl = inc - tot;
#pragma unroll
    for (int i = 0; i < 8; ++i) cs[base + i] = v[i] + excl;
  }
}

// ---------------------------------------------------------------------------
// Fused conv-GEMM + bias + ReLU + LayerNorm (+ final linear for LAST).
// Full-N block: BN=384 (all of F), BM=64 rows, 512 threads (8 waves),
// wave w owns n in [w*48, w*48+48) x all 64 m. Grid = 256 = 1 block/CU.
// D[n][m]: A = W rows (n), B = X rows (m); both frags contiguous in k.
// LAST=false: writes LN output bf16 into padded x1p rows 1..T.
// LAST=true : LN + dot(wl) + bl, masked -> dpo[B*T] f32.
template <bool LAST>
__global__ __launch_bounds__(512) void gemm_ln_kernel(
    const ushort_t* __restrict__ xp,   // [B][PT][C] bf16, zero halos
    const ushort_t* __restrict__ wt,   // [F][KTOT] bf16
    const float* __restrict__ bias,    // [F]
    const float* __restrict__ g,       // [F]
    const float* __restrict__ be,      // [F]
    const float* __restrict__ wl,      // [F]   (LAST)
    const float* __restrict__ bl,      // [1]   (LAST)
    const float* __restrict__ mask,    // [B*T] (LAST)
    ushort_t* __restrict__ xout,       // [B][PT][C] (LAST=false)
    float* __restrict__ dpo) {         // [B*T]      (LAST=true)
  __shared__ char ldsW[F_ * 128];      // [384][64] bf16, 48 KB, swizzled
  __shared__ char ldsX[64 * 128];      // [64][64] bf16, 8 KB, swizzled
  __shared__ float red[8][64][2];
  __shared__ float stats[64][2];

  const int tid = threadIdx.x;
  const int l = tid & 63, q = l >> 4, r16 = l & 15;
  const int wid = tid >> 6;            // 0..7
  const int b = blockIdx.x >> 3, t0 = (blockIdx.x & 7) * 64;
  const ushort_t* xb = xp + (size_t)b * PT * C_;

  f32x4 acc[3][4];
#pragma unroll
  for (int fn = 0; fn < 3; ++fn)
#pragma unroll
    for (int fm = 0; fm < 4; ++fm) acc[fn][fm] = (f32x4){0.f, 0.f, 0.f, 0.f};

  for (int s = 0; s < 18; ++s) {
    const int kk = s / 6, c0 = (s % 6) * 64;
    __syncthreads();  // previous tile's readers done
    // Stage W [384][64] (6 passes x 8KB) + X [64][64] (1 pass), 16B/lane.
    // Linear LDS dest, chunk-XOR swizzle via pre-swizzled global source.
#pragma unroll
    for (int i = 0; i < 6; ++i) {
      int lin = i * 8192 + tid * 16;
      int row = lin >> 7, ch = ((lin >> 4) & 7) ^ (row & 7);
      gload16(wt + (size_t)row * KTOT + kk * C_ + c0 + ch * 8,
              ldsW + i * 8192 + (wid << 10));
    }
    {
      int lin = tid * 16;
      int row = lin >> 7, ch = ((lin >> 4) & 7) ^ (row & 7);
      gload16(xb + (size_t)(t0 + row + kk) * C_ + c0 + ch * 8,
              ldsX + (wid << 10));
    }
    __syncthreads();  // staging complete

#pragma unroll
    for (int ks = 0; ks < 2; ++ks) {
      bf16x8 af[3], bx[4];
#pragma unroll
      for (int fn = 0; fn < 3; ++fn) {
        int rr = wid * 48 + fn * 16 + r16;
        int ch = (ks * 4 + q) ^ (rr & 7);
        af[fn] = *(const bf16x8*)(ldsW + rr * 128 + ch * 16);
      }
#pragma unroll
      for (int fm = 0; fm < 4; ++fm) {
        int rr = fm * 16 + r16;
        int ch = (ks * 4 + q) ^ (rr & 7);
        bx[fm] = *(const bf16x8*)(ldsX + rr * 128 + ch * 16);
      }
#pragma unroll
      for (int fn = 0; fn < 3; ++fn)
#pragma unroll
        for (int fm = 0; fm < 4; ++fm)
          acc[fn][fm] = __builtin_amdgcn_mfma_f32_16x16x32_bf16(
              af[fn], bx[fm], acc[fn][fm], 0, 0, 0);
    }
  }

  // --- epilogue: bias + ReLU (in place) ---
#pragma unroll
  for (int fn = 0; fn < 3; ++fn) {
    const int nb = wid * 48 + fn * 16 + q * 4;
    float b0 = bias[nb], b1 = bias[nb + 1], b2 = bias[nb + 2], b3 = bias[nb + 3];
#pragma unroll
    for (int fm = 0; fm < 4; ++fm) {
      acc[fn][fm][0] = fmaxf(acc[fn][fm][0] + b0, 0.f);
      acc[fn][fm][1] = fmaxf(acc[fn][fm][1] + b1, 0.f);
      acc[fn][fm][2] = fmaxf(acc[fn][fm][2] + b2, 0.f);
      acc[fn][fm][3] = fmaxf(acc[fn][fm][3] + b3, 0.f);
    }
  }

  // --- LN stats: per-m sum/sumsq over the wave's 48 n, then cross-wave ---
#pragma unroll
  for (int fm = 0; fm < 4; ++fm) {
    float s = 0.f, s2 = 0.f;
#pragma unroll
    for (int fn = 0; fn < 3; ++fn)
#pragma unroll
      for (int j = 0; j < 4; ++j) {
        float v = acc[fn][fm][j];
        s += v; s2 += v * v;
      }
    s += __shfl_xor(s, 16); s += __shfl_xor(s, 32);
    s2 += __shfl_xor(s2, 16); s2 += __shfl_xor(s2, 32);
    if (l < 16) { red[wid][fm * 16 + r16][0] = s; red[wid][fm * 16 + r16][1] = s2; }
  }
  __syncthreads();
  if (tid < 64) {
    float S = 0.f, S2 = 0.f;
#pragma unroll
    for (int w = 0; w < 8; ++w) { S += red[w][tid][0]; S2 += red[w][tid][1]; }
    float mu = S / F_;
    stats[tid][0] = mu;
    stats[tid][1] = rsqrtf(S2 / F_ - mu * mu + 1e-5f);
  }
  __syncthreads();

  if (!LAST) {
#pragma unroll
    for (int fn = 0; fn < 3; ++fn) {
      const int nb = wid * 48 + fn * 16 + q * 4;
      float g0 = g[nb], g1 = g[nb + 1], g2 = g[nb + 2], g3 = g[nb + 3];
      float e0 = be[nb], e1 = be[nb + 1], e2 = be[nb + 2], e3 = be[nb + 3];
#pragma unroll
      for (int fm = 0; fm < 4; ++fm) {
        const int m = fm * 16 + r16;
        const float mu = stats[m][0], rs = stats[m][1];
        float a0 = (acc[fn][fm][0] - mu) * rs * g0 + e0;
        float a1 = (acc[fn][fm][1] - mu) * rs * g1 + e1;
        float a2 = (acc[fn][fm][2] - mu) * rs * g2 + e2;
        float a3 = (acc[fn][fm][3] - mu) * rs * g3 + e3;
        uint32_t p0 = (uint32_t)f2bf(a0) | ((uint32_t)f2bf(a1) << 16);
        uint32_t p1 = (uint32_t)f2bf(a2) | ((uint32_t)f2bf(a3) << 16);
        *(uint2*)(xout + ((size_t)(b * PT + 1 + t0 + m)) * C_ + nb) =
            make_uint2(p0, p1);
      }
    }
  } else {
    float p[4] = {0.f, 0.f, 0.f, 0.f};
#pragma unroll
    for (int fn = 0; fn < 3; ++fn) {
      const int nb = wid * 48 + fn * 16 + q * 4;
      float g0 = g[nb], g1 = g[nb + 1], g2 = g[nb + 2], g3 = g[nb + 3];
      float e0 = be[nb], e1 = be[nb + 1], e2 = be[nb + 2], e3 = be[nb + 3];
      float l0 = wl[nb], l1 = wl[nb + 1], l2 = wl[nb + 2], l3 = wl[nb + 3];
#pragma unroll
      for (int fm = 0; fm < 4; ++fm) {
        const int m = fm * 16 + r16;
        const float mu = stats[m][0], rs = stats[m][1];
        p[fm] += ((acc[fn][fm][0] - mu) * rs * g0 + e0) * l0 +
                 ((acc[fn][fm][1] - mu) * rs * g1 + e1) * l1 +
                 ((acc[fn][fm][2] - mu) * rs * g2 + e2) * l2 +
                 ((acc[fn][fm][3] - mu) * rs * g3 + e3) * l3;
      }
    }
    __syncthreads();  // red reuse
#pragma unroll
    for (int fm = 0; fm < 4; ++fm) {
      float s = p[fm];
      s += __shfl_xor(s, 16); s += __shfl_xor(s, 32);
      if (l < 16) red[wid][fm * 16 + r16][0] = s;
    }
    __syncthreads();
    if (tid < 64) {
      float S = 0.f;
#pragma unroll
      for (int w = 0; w < 8; ++w) S += red[w][tid][0];
      int t = t0 + tid;
      dpo[b * T_ + t] = (S + bl[0]) * mask[b * T_ + t];
    }
  }
}

// ---------------------------------------------------------------------------
__global__ __launch_bounds__(256) void expand_kernel(
    const float* __restrict__ enc,  // [B,T,C] f32
    const int* __restrict__ cs,     // [B,T]
    float* __restrict__ out,        // [B,M,C]
    float* __restrict__ dec) {      // [B,M] (as float)
  __shared__ int scs[T_];
  const int blk = blockIdx.x;  // B * (M/4) blocks
  const int b = blk / (M_ / 4);
  const int p0 = (blk - b * (M_ / 4)) * 4;
  for (int i = threadIdx.x; i < T_; i += 256) scs[i] = cs[b * T_ + i];
  __syncthreads();

  const int lane = threadIdx.x & 63;
  const int wid = threadIdx.x >> 6;
  const int pos = p0 + wid;
  const int total = scs[T_ - 1];
  const bool valid = pos < total;

  int idx = 0;
#pragma unroll
  for (int step = 512; step; step >>= 1)
    if (idx + step <= T_ && scs[idx + step - 1] <= pos) idx += step;
  int src = idx < T_ ? idx : T_ - 1;

  const float4* srow = (const float4*)(enc + ((size_t)b * T_ + src) * C_);
  float4* orow = (float4*)(out + ((size_t)b * M_ + pos) * C_);
  const float4 zero = make_float4(0.f, 0.f, 0.f, 0.f);
#pragma unroll
  for (int j = 0; j < 2; ++j) {
    int c4 = j * 64 + lane;
    if (c4 < C_ / 4) orow[c4] = valid ? srow[c4] : zero;
  }
  if (lane == 0) dec[b * M_ + pos] = valid ? (float)(pos + 1) : 0.f;
}

// ---------------------------------------------------------------------------
extern "C" void kernel_launch(void* const* d_in, const int* in_sizes, int n_in,
                              void* d_out, int out_size, void* d_ws,
                              size_t ws_size, hipStream_t stream) {
  const float* enc    = (const float*)d_in[0];
  const float* mask   = (const float*)d_in[1];
  const int*   target = (const int*)d_in[2];
  const float* w1    = (const float*)d_in[4];
  const float* b1    = (const float*)d_in[5];
  const float* g1    = (const float*)d_in[6];
  const float* beta1 = (const float*)d_in[7];
  const float* w2    = (const float*)d_in[8];
  const float* b2    = (const float*)d_in[9];
  const float* g2    = (const float*)d_in[10];
  const float* beta2 = (const float*)d_in[11];
  const float* wl    = (const float*)d_in[12];
  const float* bl    = (const float*)d_in[13];

  // Workspace (bf16): xm | x1p (both padded) | wt1 | wt2 | cs (i32)
  ushort_t* xm  = (ushort_t*)d_ws;                    // [B][PT][C]
  ushort_t* x1p = xm + (size_t)B_ * PT * C_;          // [B][PT][C]
  ushort_t* wt1 = x1p + (size_t)B_ * PT * C_;         // [F][KTOT]
  ushort_t* wt2 = wt1 + (size_t)F_ * KTOT;
  int*      cs  = (int*)(wt2 + (size_t)F_ * KTOT);    // [B][T]

  float* out0 = (float*)d_out;                        // [B,M,C]
  float* dec  = out0 + (size_t)B_ * M_ * C_;          // [B,M]
  float* dpo  = dec + (size_t)B_ * M_;                // [B,T]

  prep_kernel<<<NXB + NWB + 8, 256, 0, stream>>>(
      enc, mask, target, w1, w2, xm, x1p, wt1, wt2, cs);

  gemm_ln_kernel<false><<<B_ * (T_ / 64), 512, 0, stream>>>(
      xm, wt1, b1, g1, beta1, nullptr, nullptr, nullptr, x1p, nullptr);
  gemm_ln_kernel<true><<<B_ * (T_ / 64), 512, 0, stream>>>(
      x1p, wt2, b2, g2, beta2, wl, bl, mask, nullptr, dpo);

  expand_kernel<<<(B_ * M_) / 4, 256, 0, stream>>>(enc, cs, out0, dec);
}